// Round 8
// baseline (154.432 us; speedup 1.0000x reference)
//
#include <hip/hip_runtime.h>
#include <stdint.h>

// BlockAttention fused via augmented Gram matrix, BARRIER-FREE chunk loop.
// B=8,S=8192,D=H=128, BLOCK=256, WINDOW=256 (halo 255).
// out_blk = Q_blk * (scale * Kwin^T Vwin);  with xt=[x,1]:
//   M^T = Wv~ Gt Wk~^T * scale,  Gt = sum_{s in win} xt_s xt_s^T (129x129 sym).
// Chunk loop: each wave gathers its own MFMA A/B frags DIRECTLY from global x
// (lane=d, coalesced 128B per half-wave) and accumulates <=2 Gram tiles in
// regs. No LDS, no __syncthreads in the loop -> loads stay in flight.
// Final phase (r7, proven): Gt->LDS, P=Wv~Gt, M^T=P Wk~^T, q-proj + O.

#define B_ 8
#define S_ 8192
#define LDG 164    // Gt / P LDS leading dim (shorts)
#define LDM 132    // M^T LDS leading dim (shorts)
#define LDQP 36    // per-wave q patch LD (shorts)
#define PLOFF 52480    // pl region offset (gl = 160*164*2 = 52480 B)
#define QPOFF 94464    // qpat offset (pl = 128*164*2 = 41984)
#define SMEMSZ 112896  // + qpat 8*32*36*2 = 18432

using bf16x4 = __attribute__((ext_vector_type(4))) short;
using bf16x8 = __attribute__((ext_vector_type(8))) short;
using f32x16 = __attribute__((ext_vector_type(16))) float;

__device__ __forceinline__ short f2bf(float f) {
  union { float f; uint32_t u; } v; v.f = f;
  uint32_t r = v.u + 0x7fffu + ((v.u >> 16) & 1u);   // RNE
  return (short)(r >> 16);
}

__device__ __forceinline__ bf16x8 cvt8(float4 a, float4 b) {
  bf16x8 r;
  r[0] = f2bf(a.x); r[1] = f2bf(a.y); r[2] = f2bf(a.z); r[3] = f2bf(a.w);
  r[4] = f2bf(b.x); r[5] = f2bf(b.y); r[6] = f2bf(b.z); r[7] = f2bf(b.w);
  return r;
}

__device__ __forceinline__ bf16x8 ld8(const short* p) {   // 8B-aligned LDS read
  bf16x4 lo = *(const bf16x4*)p;
  bf16x4 hi = *(const bf16x4*)(p + 4);
  return __builtin_shufflevector(lo, hi, 0, 1, 2, 3, 4, 5, 6, 7);
}

__global__ __launch_bounds__(512, 2) void fused_kernel(
    const float* __restrict__ x,
    const float* __restrict__ Wq, const float* __restrict__ bq,
    const float* __restrict__ Wk, const float* __restrict__ bk,
    const float* __restrict__ Wv, const float* __restrict__ bv,
    float* __restrict__ out)
{
  __shared__ __align__(16) char smem[SMEMSZ];
  short* gl = (short*)smem;                       // 160 x LDG (zero-padded)

  const int tid  = threadIdx.x;
  const int lane = tid & 63;
  const int wv   = tid >> 6;        // 0..7
  const int c    = lane & 31;
  const int hl   = lane >> 5;

  const int swz = (blockIdx.x & 7) * 32 + (blockIdx.x >> 3);  // XCD swizzle
  const int b   = swz >> 5;
  const int n   = swz & 31;

  const int win_lo = (n == 0) ? 0 : n * 256 - 255;
  const int win_hi = (n == 31) ? S_ : n * 256 + 511;   // exclusive
  const int jlo    = (n == 0) ? 4 : 0;
  const int jhi    = (n == 31) ? 8 : 12;
  const int cbase  = n * 256 - 256;

  const float* xb = x + (size_t)b * S_ * 128;

  // zero-init gl (3280 float4); must complete before any gwrite
  {
    float4 z = {0.f, 0.f, 0.f, 0.f};
    float4* g4 = (float4*)smem;
    #pragma unroll
    for (int i = 0; i < 7; ++i) {
      int idx = i * 512 + tid;
      if (idx < 3280) g4[idx] = z;
    }
  }
  __syncthreads();

  // per-wave Gram config: slices loaded (sA,sB), tiles (t0i,t0j),(t1i,t1j),
  // operand selectors: 0 = fragA, 1 = fragB, 2 = ones
  int sA, sB, t0i, t0j, t0bs, t1i, t1j, t1as, t1bs;
  bool hasB, hasT1;
  switch (wv) {
    case 0: sA=0; sB=0; hasB=false; t0i=0; t0j=0; t0bs=0; hasT1=false; t1i=0; t1j=0; t1as=0; t1bs=0; break;
    case 1: sA=1; sB=2; hasB=true;  t0i=1; t0j=1; t0bs=0; hasT1=true;  t1i=1; t1j=2; t1as=0; t1bs=1; break;
    case 2: sA=2; sB=3; hasB=true;  t0i=2; t0j=2; t0bs=0; hasT1=true;  t1i=2; t1j=3; t1as=0; t1bs=1; break;
    case 3: sA=3; sB=0; hasB=true;  t0i=3; t0j=3; t0bs=0; hasT1=true;  t1i=0; t1j=3; t1as=1; t1bs=0; break;
    case 4: sA=0; sB=2; hasB=true;  t0i=0; t0j=2; t0bs=1; hasT1=true;  t1i=0; t1j=4; t1as=0; t1bs=2; break;
    case 5: sA=1; sB=3; hasB=true;  t0i=1; t0j=3; t0bs=1; hasT1=true;  t1i=1; t1j=4; t1as=0; t1bs=2; break;
    case 6: sA=2; sB=3; hasB=true;  t0i=2; t0j=4; t0bs=2; hasT1=true;  t1i=3; t1j=4; t1as=1; t1bs=2; break;
    default:sA=0; sB=1; hasB=true;  t0i=0; t0j=1; t0bs=1; hasT1=false; t1i=0; t1j=0; t1as=0; t1bs=0; break;
  }
  const bool needOnes = (t0bs == 2) || (hasT1 && t1bs == 2);

  // gather one chunk's A-frags from global: fr[sl][kst], lane (c,hl) holds
  // xt^T[slice*32+c][s = c0+16kst+8hl+j]  = x[c0+16kst+8hl+j][slice*32+c]
  auto loadFrags = [&](int c0, bf16x8 (&fr)[2][4]) {
    const bool mk = (c0 < win_lo) | (c0 + 64 > win_hi);
    #pragma unroll
    for (int sl = 0; sl < 2; ++sl) {
      if (sl == 1 && !hasB) break;
      const float* base = xb + (size_t)c0 * 128 + ((sl ? sB : sA) * 32 + c) + hl * 8 * 128;
      #pragma unroll
      for (int kst = 0; kst < 4; ++kst) {
        float v[8];
        #pragma unroll
        for (int j2 = 0; j2 < 8; ++j2)
          v[j2] = base[(kst * 16 + j2) * 128];
        if (mk) {
          #pragma unroll
          for (int j2 = 0; j2 < 8; ++j2) {
            const int sg = c0 + kst * 16 + hl * 8 + j2;
            if (sg < win_lo || sg >= win_hi) v[j2] = 0.f;
          }
        }
        bf16x8 r;
        #pragma unroll
        for (int j2 = 0; j2 < 8; ++j2) r[j2] = f2bf(v[j2]);
        fr[sl][kst] = r;
      }
    }
  };

  auto onesFrags = [&](int c0, bf16x8 (&ob)[4]) {
    const bool mk = (c0 < win_lo) | (c0 + 64 > win_hi);
    #pragma unroll
    for (int kst = 0; kst < 4; ++kst) {
      bf16x8 r;
      #pragma unroll
      for (int j2 = 0; j2 < 8; ++j2) {
        const int sg = c0 + kst * 16 + hl * 8 + j2;
        r[j2] = (!mk || (sg >= win_lo && sg < win_hi)) ? (short)0x3F80 : (short)0;
      }
      ob[kst] = r;
    }
  };

  f32x16 gacc0, gacc1;
  #pragma unroll
  for (int i = 0; i < 16; ++i) { gacc0[i] = 0.f; gacc1[i] = 0.f; }

  auto gramChunk = [&](bf16x8 (&fr)[2][4], bf16x8 (&ob)[4]) {
    #pragma unroll
    for (int kst = 0; kst < 4; ++kst) {
      bf16x8 b0 = (t0bs == 0) ? fr[0][kst] : ((t0bs == 1) ? fr[1][kst] : ob[kst]);
      gacc0 = __builtin_amdgcn_mfma_f32_32x32x16_bf16(fr[0][kst], b0, gacc0, 0, 0, 0);
      if (hasT1) {
        bf16x8 a1 = (t1as == 0) ? fr[0][kst] : fr[1][kst];
        bf16x8 b1 = (t1bs == 0) ? fr[0][kst] : ((t1bs == 1) ? fr[1][kst] : ob[kst]);
        gacc1 = __builtin_amdgcn_mfma_f32_32x32x16_bf16(a1, b1, gacc1, 0, 0, 0);
      }
    }
  };

  // -------- barrier-free chunk loop (double-banked fragment regs) --------
  bf16x8 fr0[2][4], fr1[2][4], ob[4];
  loadFrags(cbase + jlo * 64, fr0);
  for (int j = jlo; j < jhi; ++j) {
    const int c0 = cbase + j * 64;
    const bool more = (j + 1 < jhi);
    if (needOnes) onesFrags(c0, ob);
    if (((j - jlo) & 1) == 0) {
      if (more) loadFrags(c0 + 64, fr1);
      gramChunk(fr0, ob);
    } else {
      if (more) loadFrags(c0 + 64, fr0);
      gramChunk(fr1, ob);
    }
  }

  // -------- write Gt (scaled bf16) with symmetric mirrors --------
  const float scale = 0.08838834764831845f;   // 1/sqrt(128)
  auto gwrite = [&](f32x16& g, int ti, int tj) {
    if (tj == 4) {
      if (c == 0) {   // all C-columns identical; 2 lanes (hl=0,1) write 32 rows
        #pragma unroll
        for (int reg = 0; reg < 16; ++reg) {
          const int row = ti * 32 + (reg & 3) + 8 * (reg >> 2) + 4 * hl;
          const short v = f2bf(g[reg] * scale);
          gl[row * LDG + 128] = v;
          gl[128 * LDG + row] = v;
        }
      }
    } else {
      #pragma unroll
      for (int reg = 0; reg < 16; ++reg) {
        const int row = ti * 32 + (reg & 3) + 8 * (reg >> 2) + 4 * hl;
        gl[row * LDG + tj * 32 + c] = f2bf(g[reg] * scale);
      }
      if (ti != tj) {
        short* dst = gl + (tj * 32 + c) * LDG + ti * 32;
        #pragma unroll
        for (int g4 = 0; g4 < 4; ++g4) {
          #pragma unroll
          for (int p = 0; p < 2; ++p) {
            const int reg = g4 * 4 + p * 2;
            const int rl  = g4 * 8 + hl * 4 + p * 2;
            const uint32_t pk = (uint32_t)(uint16_t)f2bf(g[reg] * scale) |
                                ((uint32_t)(uint16_t)f2bf(g[reg + 1] * scale) << 16);
            *(uint32_t*)(dst + rl) = pk;
          }
        }
      }
    }
  };
  gwrite(gacc0, t0i, t0j);
  if (hasT1) gwrite(gacc1, t1i, t1j);
  if (tid == 0)
    gl[128 * LDG + 128] = f2bf((float)(win_hi - win_lo) * scale);

  // prefetch this wave's q-row x fragments (overlaps gwrite + barrier)
  bf16x8 aq[8];
  {
    const float* xr = xb + (size_t)(n * 256 + wv * 32 + c) * 128 + hl * 8;
    #pragma unroll
    for (int kst = 0; kst < 8; ++kst) {
      float4 f0 = *(const float4*)(xr + kst * 16);
      float4 f1 = *(const float4*)(xr + kst * 16 + 4);
      aq[kst] = cvt8(f0, f1);
    }
  }
  __syncthreads();   // B1: Gt complete

  // GEMM1: P = Wv~ * Gt  (waves 0-3: ht=wv, d1t 0-2; waves 4-7: ht=wv-4, 3-4)
  short* pl = (short*)(smem + PLOFF);
  {
    const int ht = wv & 3;
    const bool lo = (wv < 4);
    const int nd1 = lo ? 3 : 2;
    const int d1b = lo ? 0 : 3;
    const int hr = ht * 32 + c;
    bf16x8 av[9];
    {
      const float* wr = Wv + (size_t)hr * 128 + hl * 8;
      #pragma unroll
      for (int kst = 0; kst < 8; ++kst) {
        float4 f0 = *(const float4*)(wr + kst * 16);
        float4 f1 = *(const float4*)(wr + kst * 16 + 4);
        av[kst] = cvt8(f0, f1);
      }
      bf16x8 a8 = {};
      if (hl == 0) a8[0] = f2bf(bv[hr]);
      av[8] = a8;
    }
    f32x16 pacc[3];
    #pragma unroll
    for (int t = 0; t < 3; ++t)
      #pragma unroll
      for (int i = 0; i < 16; ++i) pacc[t][i] = 0.f;
    #pragma unroll
    for (int t = 0; t < 3; ++t) {
      if (t < nd1) {
        const int d1t = d1b + t;
        #pragma unroll
        for (int kst = 0; kst < 9; ++kst) {
          bf16x8 bb = ld8(gl + (d1t * 32 + c) * LDG + kst * 16 + hl * 8);
          pacc[t] = __builtin_amdgcn_mfma_f32_32x32x16_bf16(av[kst], bb, pacc[t], 0, 0, 0);
        }
      }
    }
    #pragma unroll
    for (int t = 0; t < 3; ++t) {
      if (t < nd1) {
        const int d1t = d1b + t;
        #pragma unroll
        for (int reg = 0; reg < 16; ++reg) {
          const int row = ht * 32 + (reg & 3) + 8 * (reg >> 2) + 4 * hl;
          pl[row * LDG + d1t * 32 + c] = f2bf(pacc[t][reg]);
        }
      }
    }
  }
  __syncthreads();   // B2: P complete

  // GEMM2: M^T = P * Wk~^T  (ht = wv>>1, d-tiles (wv&1)*2 + {0,1})
  short* m_l = gl;   // overlays Gt (dead after GEMM1, fenced by B2)
  {
    const int ht = wv >> 1;
    const int dt0 = (wv & 1) * 2;
    bf16x8 ap[9];
    {
      const short* pr = pl + (ht * 32 + c) * LDG + hl * 8;
      #pragma unroll
      for (int kst = 0; kst < 9; ++kst) ap[kst] = ld8(pr + kst * 16);
    }
    f32x16 m2[2];
    #pragma unroll
    for (int t = 0; t < 2; ++t)
      #pragma unroll
      for (int i = 0; i < 16; ++i) m2[t][i] = 0.f;
    #pragma unroll
    for (int t = 0; t < 2; ++t) {
      const int dr = (dt0 + t) * 32 + c;
      const float* wr = Wk + (size_t)dr * 128 + hl * 8;
      #pragma unroll
      for (int kst = 0; kst < 8; ++kst) {
        float4 f0 = *(const float4*)(wr + kst * 16);
        float4 f1 = *(const float4*)(wr + kst * 16 + 4);
        bf16x8 bb = cvt8(f0, f1);
        m2[t] = __builtin_amdgcn_mfma_f32_32x32x16_bf16(ap[kst], bb, m2[t], 0, 0, 0);
      }
      bf16x8 b8 = {};
      if (hl == 0) b8[0] = f2bf(bk[dr]);
      m2[t] = __builtin_amdgcn_mfma_f32_32x32x16_bf16(ap[8], b8, m2[t], 0, 0, 0);
    }
    #pragma unroll
    for (int t = 0; t < 2; ++t) {
      #pragma unroll
      for (int reg = 0; reg < 16; ++reg) {
        const int row = ht * 32 + (reg & 3) + 8 * (reg >> 2) + 4 * hl;
        m_l[row * LDM + (dt0 + t) * 32 + c] = f2bf(m2[t][reg]);
      }
    }
  }
  __syncthreads();   // B3: M^T complete

  // q-proj + O per wave (32 q-rows), pipelined per 32-col tile
  short* qpat = (short*)(smem + QPOFF) + wv * (32 * LDQP);
  float* opat = (float*)(smem + PLOFF) + wv * (32 * 36);   // pl dead post-B3

  f32x16 oacc[4];
  #pragma unroll
  for (int ht = 0; ht < 4; ++ht)
    #pragma unroll
    for (int i = 0; i < 16; ++i) oacc[ht][i] = 0.f;

  #pragma unroll
  for (int nt = 0; nt < 4; ++nt) {
    bf16x8 wqf[8];
    {
      const float* wr = Wq + (size_t)(nt * 32 + c) * 128 + hl * 8;
      #pragma unroll
      for (int kst = 0; kst < 8; ++kst) {
        float4 f0 = *(const float4*)(wr + kst * 16);
        float4 f1 = *(const float4*)(wr + kst * 16 + 4);
        wqf[kst] = cvt8(f0, f1);
      }
    }
    f32x16 qacc;
    {
      const float bb = bq[nt * 32 + c];
      #pragma unroll
      for (int i = 0; i < 16; ++i) qacc[i] = bb;
    }
    #pragma unroll
    for (int kst = 0; kst < 8; ++kst)
      qacc = __builtin_amdgcn_mfma_f32_32x32x16_bf16(aq[kst], wqf[kst], qacc, 0, 0, 0);
    #pragma unroll
    for (int reg = 0; reg < 16; ++reg) {
      const int row = (reg & 3) + 8 * (reg >> 2) + 4 * hl;
      qpat[row * LDQP + c] = f2bf(qacc[reg]);
    }
    #pragma unroll
    for (int kst2 = 0; kst2 < 2; ++kst2) {
      bf16x8 qf = ld8(qpat + c * LDQP + kst2 * 16 + hl * 8);
      #pragma unroll
      for (int ht = 0; ht < 4; ++ht) {
        bf16x8 bb = ld8(m_l + (ht * 32 + c) * LDM + nt * 32 + kst2 * 16 + hl * 8);
        oacc[ht] = __builtin_amdgcn_mfma_f32_32x32x16_bf16(qf, bb, oacc[ht], 0, 0, 0);
      }
    }
  }

  // epilogue: per-wave f32 patch -> coalesced float4 stores
  float* outb = out + ((size_t)b * S_ + n * 256 + wv * 32) * 128;
  #pragma unroll
  for (int ht = 0; ht < 4; ++ht) {
    #pragma unroll
    for (int reg = 0; reg < 16; ++reg) {
      const int row = (reg & 3) + 8 * (reg >> 2) + 4 * hl;
      opat[row * 36 + c] = oacc[ht][reg];
    }
    #pragma unroll
    for (int p = 0; p < 4; ++p) {
      const int row = p * 8 + (lane >> 3);
      float4 vv = *(const float4*)(opat + row * 36 + (lane & 7) * 4);
      *(float4*)(outb + (size_t)row * 128 + ht * 32 + (lane & 7) * 4) = vv;
    }
  }
}

// ---------------------------------------------------------------------------
extern "C" void kernel_launch(void* const* d_in, const int* in_sizes, int n_in,
                              void* d_out, int out_size, void* d_ws, size_t ws_size,
                              hipStream_t stream) {
  const float* x  = (const float*)d_in[0];
  const float* Wq = (const float*)d_in[1];
  const float* bq = (const float*)d_in[2];
  const float* Wk = (const float*)d_in[3];
  const float* bk = (const float*)d_in[4];
  const float* Wv = (const float*)d_in[5];
  const float* bv = (const float*)d_in[6];
  float* out = (float*)d_out;

  fused_kernel<<<256, 512, 0, stream>>>(x, Wq, bq, Wk, bk, Wv, bv, out);
}